// Round 3
// baseline (560.778 us; speedup 1.0000x reference)
//
#include <hip/hip_runtime.h>
#include <cstdint>
#include <cstddef>

typedef __bf16 bf16x8 __attribute__((ext_vector_type(8)));
typedef float  f32x16 __attribute__((ext_vector_type(16)));
typedef float  f32x2  __attribute__((ext_vector_type(2)));

__device__ __forceinline__ unsigned f2bf_u(float f){
  unsigned u = __float_as_uint(f);
  return (u + 0x7FFFu + ((u >> 16) & 1u)) >> 16;   // RNE
}
__device__ __forceinline__ unsigned short f2bf(float f){ return (unsigned short)f2bf_u(f); }

// clamp-free tanh on a packed pair (plain C vectors; compiler may form v_pk_*_f32).
// exp2(+inf) -> inf -> rcp -> 0 -> 1.0 exact; exp2(-inf) -> 0 -> rcp(1)=1 -> -1. Inputs finite.
__device__ __forceinline__ f32x2 tanh2v(f32x2 x){
  f32x2 e2 = x * 2.8853900817779268f;               // 2x/ln2
  f32x2 e  = { __builtin_amdgcn_exp2f(e2.x), __builtin_amdgcn_exp2f(e2.y) };
  f32x2 d  = e + 1.0f;
  f32x2 r  = { __builtin_amdgcn_rcpf(d.x), __builtin_amdgcn_rcpf(d.y) };
  return 1.0f - 2.0f * r;
}

#define MFMA(a,b,c) __builtin_amdgcn_mfma_f32_32x32x16_bf16((a),(b),(c),0,0,0)

__device__ __forceinline__ void ld_lds16(const void* g, void* l){
  __builtin_amdgcn_global_load_lds(
      (const __attribute__((address_space(1))) unsigned int*)g,
      (__attribute__((address_space(3))) unsigned int*)l, 16, 0, 0);
}
__device__ __forceinline__ bf16x8 mk_frag(uint2 lo, uint2 hi){
  return __builtin_bit_cast(bf16x8, make_uint4(lo.x, lo.y, hi.x, hi.y));
}

// ---------- prep: Wb fp32 -> bf16, swizzled into stage-1 LDS chunk order ----------
__global__ void prep_wb(const float* __restrict__ Wb, unsigned short* __restrict__ dst){
  int s  = blockIdx.x*256 + threadIdx.x;     // 65536 slots of 8B
  int r  = s & 31;
  int c  = (s>>5) & 3;
  int tj = (s>>7) & 3;
  int ks = (s>>9) & 3;
  int kq = (s>>11) & 3;
  int gc = (s>>13) & 7;
  const float* src = Wb + ((size_t)tj*256 + gc*32 + r)*256 + kq*64 + ks*16 + c*4;
  float4 f = *reinterpret_cast<const float4*>(src);
  ushort4 o; o.x=f2bf(f.x); o.y=f2bf(f.y); o.z=f2bf(f.z); o.w=f2bf(f.w);
  *reinterpret_cast<ushort4*>(dst + (size_t)s*4) = o;
}

// ---------- prep: W1/W2 fp32 -> bf16, frag-major ----------
__global__ void prep_w(const float* __restrict__ W1, const float* __restrict__ W2,
                       unsigned short* __restrict__ dst){
  int id = blockIdx.x*256 + threadIdx.x;     // 16384 slots of 16B (W1 then W2)
  const float* W = (id < 8192) ? W1 : W2;
  int s  = id & 8191;
  int l  = s & 63;
  int ks = (s>>6) & 15;
  int ct = (s>>10) & 7;
  const float* src = W + ((size_t)ct*32 + (l&31))*256 + ks*16 + (l>>5)*8;
  float4 f0 = *reinterpret_cast<const float4*>(src);
  float4 f1 = *reinterpret_cast<const float4*>(src + 4);
  ushort4 a, b;
  a.x=f2bf(f0.x); a.y=f2bf(f0.y); a.z=f2bf(f0.z); a.w=f2bf(f0.w);
  b.x=f2bf(f1.x); b.y=f2bf(f1.y); b.z=f2bf(f1.z); b.w=f2bf(f1.w);
  ushort4* d = reinterpret_cast<ushort4*>(dst + (size_t)id*8);
  d[0] = a; d[1] = b;
}

// ---------- main fused kernel ----------
// snei padded to 33 slots per column-group (breaks the 8-way ushort-scatter
// write conflict; reads stay 2-way = free).
__launch_bounds__(256, 3)
__global__ void tetra_main(const float* __restrict__ x,
                           const float* __restrict__ bb,
                           const float* __restrict__ b1,
                           const float* __restrict__ gam,
                           const float* __restrict__ bet,
                           const float* __restrict__ b2,
                           const unsigned short* __restrict__ wsWb,
                           const unsigned short* __restrict__ wsW1,
                           const unsigned short* __restrict__ wsW2,
                           float* __restrict__ out)
{
  __shared__ __align__(16) uint2 sbuf[2][2048];   // 2 x 16 KB Wb chunks
  __shared__ __align__(16) uint2 snei[2112];      // [c(64)][row(32)+1 pad] 8B slots

  constexpr int PT[12][4] = {{0,1,2,3},{0,2,3,1},{0,3,1,2},{1,0,3,2},{1,2,0,3},{1,3,2,0},
                             {2,0,1,3},{2,1,3,0},{2,3,0,1},{3,0,2,1},{3,1,0,2},{3,2,1,0}};

  const int tid  = threadIdx.x;
  const int w    = tid >> 6;
  const int lane = tid & 63;
  const int l31  = lane & 31;
  const int q    = lane >> 5;

  // ---- A tile -> registers (bf16 packed, manual RNE)
  uint4 fragA[16];
  {
    const float* arow = x + ((size_t)blockIdx.x*128 + (size_t)(w*32 + l31))*256 + q*8;
#pragma unroll
    for (int s = 0; s < 16; ++s){
      float4 f0 = *reinterpret_cast<const float4*>(arow + s*16);
      float4 f1 = *reinterpret_cast<const float4*>(arow + s*16 + 4);
      fragA[s] = make_uint4(f2bf_u(f0.x) | (f2bf_u(f0.y)<<16),
                            f2bf_u(f0.z) | (f2bf_u(f0.w)<<16),
                            f2bf_u(f1.x) | (f2bf_u(f1.y)<<16),
                            f2bf_u(f1.z) | (f2bf_u(f1.w)<<16));
    }
  }

  // bb prefetch (gc=0), folded into MFMA C-init
  float bcur[4], bnext[4];
#pragma unroll
  for (int k = 0; k < 4; ++k) bcur[k] = bb[k*256 + l31];

  auto stage = [&](int t){
    const char* g = (const char*)wsWb + (size_t)t*16384 + w*4096 + lane*16;
    char* lb = (char*)(&sbuf[t&1][0]) + w*4096;
#pragma unroll
    for (int i = 0; i < 4; ++i)
      ld_lds16(g + i*1024, lb + i*1024);
  };

  stage(0);

  // ================= stage 1 =================
  unsigned short* sn = (unsigned short*)snei;
  int t = 0;
  for (int gc = 0; gc < 8; ++gc){
    f32x16 acc[4];
#pragma unroll
    for (int k = 0; k < 4; ++k){
      float bv = bcur[k];
#pragma unroll
      for (int r = 0; r < 16; ++r) acc[k][r] = bv;
    }

#pragma unroll
    for (int kq = 0; kq < 4; ++kq, ++t){
      __syncthreads();                       // sbuf[t&1] ready; sbuf[(t+1)&1] free
      if (t < 31) stage(t+1);
      const uint2* B = sbuf[t&1];
      const int boff = q*64 + l31;
#pragma unroll
      for (int ks = 0; ks < 4; ++ks){
        bf16x8 av = __builtin_bit_cast(bf16x8, fragA[kq*4 + ks]);
#pragma unroll
        for (int tj = 0; tj < 4; ++tj){
          int idx = (ks*16 + tj*4)*32 + boff;
          uint2 lo = B[idx], hi = B[idx + 32];
          acc[tj] = MFMA(av, mk_frag(lo, hi), acc[tj]);
        }
      }
    }

    // prefetch next gc's bb (drained at next gc's first barrier, hidden under epilogue)
#pragma unroll
    for (int k = 0; k < 4; ++k) bnext[k] = bb[k*256 + ((gc+1)&7)*32 + l31];

    // epilogue: clamp-free tanh packed across nb-pairs (plain C f32x2) + 12-perm combine
    const int col   = gc*32 + l31;
    const int sbase = (col>>2)*132 + (col&3);
#pragma unroll
    for (int npair = 0; npair < 2; ++npair){
      const int nb0 = 2*npair, nb1 = nb0 + 1;
      f32x2 th[4][4];     // th[k][t] = (tanh @ nb0, tanh @ nb1), same vertex t
#pragma unroll
      for (int k = 0; k < 4; ++k)
#pragma unroll
        for (int t2 = 0; t2 < 4; ++t2){
          f32x2 a = { acc[k][nb0*4 + t2], acc[k][nb1*4 + t2] };
          th[k][t2] = tanh2v(a);
        }
      float s0 = 0.0f, s1 = 0.0f;
#pragma unroll
      for (int p = 0; p < 12; ++p){
        f32x2 v = (th[0][PT[p][0]] + th[1][PT[p][1]])
                + (th[2][PT[p][2]] + th[3][PT[p][3]]);
        s0 += fmaxf(v.x, 0.0f);
        s1 += fmaxf(v.y, 0.0f);
      }
      sn[sbase + (w*8 + 2*nb0 + q)*4] = f2bf(s0 * (1.0f/3.0f));
      sn[sbase + (w*8 + 2*nb1 + q)*4] = f2bf(s1 * (1.0f/3.0f));
    }

#pragma unroll
    for (int k = 0; k < 4; ++k) bcur[k] = bnext[k];
  }

  // b1 for stage-2 C-init: issue before the barrier
  float b1v0 = b1[(w*2+0)*32 + l31];
  float b1v1 = b1[(w*2+1)*32 + l31];
  __syncthreads();   // nei3 complete

  // ================= stage 2: z = (nei/3)@W1^T (+b1 in C-init); h = relu(z*inv*gamma+beta) =================
  const int ct0 = w*2, ct1 = w*2 + 1;
  f32x16 a2[2];
#pragma unroll
  for (int r = 0; r < 16; ++r){ a2[0][r] = b1v0; a2[1][r] = b1v1; }
  {
    const uint4* W1f = (const uint4*)wsW1;
    uint4 bp[8][2];
#pragma unroll
    for (int i = 0; i < 8; ++i){
      bp[i][0] = W1f[(ct0*16 + i)*64 + lane];
      bp[i][1] = W1f[(ct1*16 + i)*64 + lane];
    }
#pragma unroll
    for (int ks = 0; ks < 16; ++ks){
      int ai = (ks*4 + q*2)*33 + l31;
      uint2 lo = snei[ai], hi = snei[ai + 33];
      bf16x8 av = mk_frag(lo, hi);
      uint4 c0 = bp[ks&7][0], c1 = bp[ks&7][1];
      if (ks < 8){
        bp[ks][0] = W1f[(ct0*16 + ks + 8)*64 + lane];
        bp[ks][1] = W1f[(ct1*16 + ks + 8)*64 + lane];
      }
      a2[0] = MFMA(av, __builtin_bit_cast(bf16x8, c0), a2[0]);
      a2[1] = MFMA(av, __builtin_bit_cast(bf16x8, c1), a2[1]);
    }
  }
  // gamma/beta/b2 loads (hidden before the barrier)
  float gvv[2], btv[2], b2v[2];
#pragma unroll
  for (int tj = 0; tj < 2; ++tj){
    int colx = (w*2 + tj)*32 + l31;
    gvv[tj] = gam[colx]; btv[tj] = bet[colx]; b2v[tj] = b2[colx];
  }
  __syncthreads();   // all snei reads done before overwrite
  {
    const float inv = 0.9999950000374998f;   // 1/sqrt(1+1e-5)
#pragma unroll
    for (int tj = 0; tj < 2; ++tj){
      int colx = (w*2 + tj)*32 + l31;
      float gs  = gvv[tj]*inv;
      float btc = btv[tj];
      int cb = (colx>>2)*132 + (colx&3);
#pragma unroll
      for (int r = 0; r < 16; ++r){
        int row = (r&3) + 8*(r>>2) + 4*q;
        sn[cb + row*4] = f2bf(fmaxf(a2[tj][r]*gs + btc, 0.0f));
      }
    }
  }
  __syncthreads();   // h complete

  // ================= stage 3: out = h@W2^T (+b2 in C-init) =================
  f32x16 a3[2];
#pragma unroll
  for (int r = 0; r < 16; ++r){ a3[0][r] = b2v[0]; a3[1][r] = b2v[1]; }
  {
    const uint4* W2f = (const uint4*)wsW2;
    uint4 bp[8][2];
#pragma unroll
    for (int i = 0; i < 8; ++i){
      bp[i][0] = W2f[(ct0*16 + i)*64 + lane];
      bp[i][1] = W2f[(ct1*16 + i)*64 + lane];
    }
#pragma unroll
    for (int ks = 0; ks < 16; ++ks){
      int ai = (ks*4 + q*2)*33 + l31;
      uint2 lo = snei[ai], hi = snei[ai + 33];
      bf16x8 av = mk_frag(lo, hi);
      uint4 c0 = bp[ks&7][0], c1 = bp[ks&7][1];
      if (ks < 8){
        bp[ks][0] = W2f[(ct0*16 + ks + 8)*64 + lane];
        bp[ks][1] = W2f[(ct1*16 + ks + 8)*64 + lane];
      }
      a3[0] = MFMA(av, __builtin_bit_cast(bf16x8, c0), a3[0]);
      a3[1] = MFMA(av, __builtin_bit_cast(bf16x8, c1), a3[1]);
    }
  }
#pragma unroll
  for (int tj = 0; tj < 2; ++tj){
    int colx = (w*2 + tj)*32 + l31;
#pragma unroll
    for (int r = 0; r < 16; ++r){
      int row = (r&3) + 8*(r>>2) + 4*q;
      out[((size_t)blockIdx.x*32 + row)*256 + colx] = a3[tj][r];
    }
  }
}

extern "C" void kernel_launch(void* const* d_in, const int* in_sizes, int n_in,
                              void* d_out, int out_size, void* d_ws, size_t ws_size,
                              hipStream_t stream)
{
  (void)n_in; (void)out_size; (void)ws_size;
  const float* x   = (const float*)d_in[0];
  const float* Wb  = (const float*)d_in[1];
  const float* bb  = (const float*)d_in[2];
  const float* W1  = (const float*)d_in[3];
  const float* b1  = (const float*)d_in[4];
  const float* gam = (const float*)d_in[5];
  const float* bet = (const float*)d_in[6];
  const float* W2  = (const float*)d_in[7];
  const float* b2  = (const float*)d_in[8];
  // d_in[9] = perms: fixed A4 rotation table, baked into the kernel.
  float* out = (float*)d_out;

  unsigned short* wsWb = (unsigned short*)d_ws;        // 512 KB
  unsigned short* wsW1 = wsWb + 262144;                // 128 KB
  unsigned short* wsW2 = wsW1 + 65536;                 // 128 KB  (768 KB total)

  prep_wb<<<dim3(256), dim3(256), 0, stream>>>(Wb, wsWb);
  prep_w <<<dim3(64),  dim3(256), 0, stream>>>(W1, W2, wsW1);

  const int N = in_sizes[0] / (4*256);   // 65536
  tetra_main<<<dim3(N/32), dim3(256), 0, stream>>>(x, bb, b1, gam, bet, b2,
                                                   wsWb, wsW1, wsW2, out);
}